// Round 6
// baseline (269.197 us; speedup 1.0000x reference)
//
#include <hip/hip_runtime.h>

#define NN 50000
#define NE 800000
#define NB 196          // ceil(NN/256) node buckets of 256 nodes
#define NBG 392         // 2*NB (both graphs)
#define NBLK 128        // edge chunks
#define CHUNK 6250      // NE / NBLK exactly
#define MAXB 6144       // max edges per bucket (mean 4081; +32 sigma)
// D = 128 features, HEADS=8, HID=16

typedef __bf16 bf16x8 __attribute__((ext_vector_type(8)));
typedef float  f32x4  __attribute__((ext_vector_type(4)));

__device__ __forceinline__ unsigned short f2bf(float x) {
    unsigned u = __float_as_uint(x);
    return (unsigned short)((u + 0x7FFFu + ((u >> 16) & 1u)) >> 16);   // RNE
}
__device__ __forceinline__ float bflo(unsigned u) { return __uint_as_float(u << 16); }
__device__ __forceinline__ float bfhi(unsigned u) { return __uint_as_float(u & 0xFFFF0000u); }
__device__ __forceinline__ unsigned pack2(float a, float b) {
    return (unsigned)f2bf(a) | ((unsigned)f2bf(b) << 16);
}

// ---------------- phase A: per-chunk LDS histogram (chunk-major histG) + W convert ----
__global__ __launch_bounds__(1024) void histA_kernel(
    const int* __restrict__ dst1, const int* __restrict__ dst2, int* __restrict__ histG,
    const float* __restrict__ Wa, const float* __restrict__ Wb,
    unsigned short* __restrict__ Wta, unsigned short* __restrict__ Wtb)
{
    const int t = threadIdx.x, blk = blockIdx.x;
    if (blk >= NBLK) {   // W convert
        const float* W = (blk - NBLK) ? Wb : Wa;
        unsigned short* Wt = (blk - NBLK) ? Wtb : Wta;
        for (int j = t; j < 128 * 128; j += 1024) {
            int n = j >> 7, k = j & 127;
            Wt[j] = f2bf(W[k * 128 + n]);
        }
        return;
    }
    __shared__ int h[NBG];
    for (int i = t; i < NBG; i += 1024) h[i] = 0;
    __syncthreads();
    const int base = blk * CHUNK;
    for (int i = t; i < CHUNK; i += 1024) {
        atomicAdd(&h[dst1[base + i] >> 8], 1);
        atomicAdd(&h[NB + (dst2[base + i] >> 8)], 1);
    }
    __syncthreads();
    for (int i = t; i < NBG; i += 1024)
        histG[blk * NBG + i] = h[i];
}

// ---------------- phase C: scatter with LOCAL prefix computation ---------------------
__global__ __launch_bounds__(1024) void scatterC_kernel(
    const int* __restrict__ src1, const int* __restrict__ dst1,
    const int* __restrict__ src2, const int* __restrict__ dst2,
    const int* __restrict__ histG,
    int* __restrict__ gbbase, int* __restrict__ gbtot,
    unsigned int* __restrict__ bin1, unsigned int* __restrict__ bin2)
{
    __shared__ int s[512];
    __shared__ int pos[NBG];
    const int t = threadIdx.x, blk = blockIdx.x;

    int total_i = 0, pref_i = 0;
    if (t < NBG) {
        for (int c = 0; c < NBLK; c++) {
            int v = histG[c * NBG + t];          // coalesced across t
            total_i += v;
            if (c < blk) pref_i += v;
        }
    }
    if (t < 512) s[t] = (t < NBG) ? total_i : 0;
    __syncthreads();
    for (int off = 1; off < 512; off <<= 1) {
        int x = 0;
        if (t < 512 && t >= off) x = s[t - off];
        __syncthreads();
        if (t < 512) s[t] += x;
        __syncthreads();
    }
    const int sumG1 = s[NB - 1];   // inclusive over graph-1 buckets
    if (t < NBG) {
        int excl = s[t] - total_i;
        int bb = excl - ((t >= NB) ? sumG1 : 0);   // per-graph exclusive base
        pos[t] = bb + pref_i;
        if (blk == 0) { gbbase[t] = bb; gbtot[t] = total_i; }
    }
    __syncthreads();

    const int base = blk * CHUNK;
    for (int i = t; i < CHUNK; i += 1024) {
        int d = dst1[base + i], sv = src1[base + i];
        int slot = atomicAdd(&pos[d >> 8], 1);
        bin1[slot] = ((unsigned)(d & 255) << 16) | (unsigned)sv;
        d = dst2[base + i]; sv = src2[base + i];
        slot = atomicAdd(&pos[NB + (d >> 8)], 1);
        bin2[slot] = ((unsigned)(d & 255) << 16) | (unsigned)sv;
    }
}

// ---------------- bucket sort: LDS counting sort per bucket, coalesced csr flush ------
__global__ __launch_bounds__(256) void bucket_sort_kernel(
    const unsigned int* __restrict__ bin1, const unsigned int* __restrict__ bin2,
    const int* __restrict__ bbase, const int* __restrict__ btot,
    unsigned short* __restrict__ csr1, int* __restrict__ start1, int* __restrict__ deg1,
    unsigned short* __restrict__ csr2, int* __restrict__ start2, int* __restrict__ deg2)
{
    __shared__ int lcnt[256];
    __shared__ int sc[256];
    __shared__ int oat[256];
    __shared__ unsigned short outb[MAXB];
    const int t = threadIdx.x;
    const int g = (blockIdx.x >= NB) ? 1 : 0;
    const int b = blockIdx.x - g * NB;
    const unsigned int* bin = g ? bin2 : bin1;
    unsigned short* csr = g ? csr2 : csr1;
    int* start = g ? start2 : start1;
    int* deg   = g ? deg2 : deg1;

    const int base = bbase[g * NB + b];
    const int tot = min(btot[g * NB + b], MAXB);

    lcnt[t] = 0;
    __syncthreads();
    for (int i = t; i < tot; i += 256) atomicAdd(&lcnt[bin[base + i] >> 16], 1);
    __syncthreads();
    sc[t] = lcnt[t];
    __syncthreads();
    for (int off = 1; off < 256; off <<= 1) {
        int x = (t >= off) ? sc[t - off] : 0;
        __syncthreads();
        sc[t] += x;
        __syncthreads();
    }
    const int ex = sc[t] - lcnt[t];
    oat[t] = ex;
    __syncthreads();
    for (int i = t; i < tot; i += 256) {
        unsigned v = bin[base + i];
        int slot = atomicAdd(&oat[v >> 16], 1);
        outb[slot] = (unsigned short)(v & 0xFFFFu);
    }
    __syncthreads();
    for (int i = t; i < tot; i += 256) csr[base + i] = outb[i];
    int nd = b * 256 + t;
    if (nd < NN) { start[nd] = base + ex; deg[nd] = lcnt[t]; }
}

// ---------------- MFMA GEMM (fp32 in): Ybf = bf16(X @ W + bias) -----------------------
__global__ __launch_bounds__(256) void mfma_gemm_kernel(
    const float* __restrict__ X, const unsigned short* __restrict__ Wt,
    const float* __restrict__ bias, unsigned short* __restrict__ Ybf, int nrows)
{
    __shared__ unsigned short Wl[128 * 128];   // 32 KB, granule-swizzled
    const int t = threadIdx.x;
    const int lane = t & 63;
    const int wv = t >> 6;
    const int row0 = blockIdx.x * 64;
    const int m16 = lane & 15;
    const int quad = lane >> 4;

    {
        const uint4* Wg = (const uint4*)Wt;
        #pragma unroll
        for (int i = 0; i < 8; i++) {
            int gi = t + i * 256;
            int n = gi >> 4, g = gi & 15;
            uint4 v = Wg[gi];
            *(uint4*)&Wl[n * 128 + (((g ^ (n & 15)) << 3))] = v;
        }
    }

    const int arow = row0 + wv * 16 + m16;
    const bool valid = (arow < nrows);
    const float4* X4 = (const float4*)X;
    float4 xr[8];
    #pragma unroll
    for (int kc = 0; kc < 4; kc++) {
        if (valid) {
            int gidx = arow * 32 + kc * 8 + quad * 2;
            xr[kc * 2]     = X4[gidx];
            xr[kc * 2 + 1] = X4[gidx + 1];
        } else {
            xr[kc * 2] = xr[kc * 2 + 1] = make_float4(0.f, 0.f, 0.f, 0.f);
        }
    }
    __syncthreads();

    f32x4 acc[8];
    #pragma unroll
    for (int nt = 0; nt < 8; nt++) acc[nt] = (f32x4){0.f, 0.f, 0.f, 0.f};

    #pragma unroll
    for (int kc = 0; kc < 4; kc++) {
        union { unsigned short u[8]; bf16x8 v; } ah, al;
        float f[8] = { xr[kc*2].x, xr[kc*2].y, xr[kc*2].z, xr[kc*2].w,
                       xr[kc*2+1].x, xr[kc*2+1].y, xr[kc*2+1].z, xr[kc*2+1].w };
        #pragma unroll
        for (int j = 0; j < 8; j++) {
            unsigned u = __float_as_uint(f[j]);
            ah.u[j] = (unsigned short)(u >> 16);
            al.u[j] = f2bf(f[j] - __uint_as_float(u & 0xFFFF0000u));
        }
        const int sgbase = (kc * 4 + quad);
        #pragma unroll
        for (int nt = 0; nt < 8; nt++) {
            const int n = nt * 16 + m16;
            bf16x8 b = *(const bf16x8*)&Wl[n * 128 + ((sgbase ^ m16) << 3)];
            acc[nt] = __builtin_amdgcn_mfma_f32_16x16x32_bf16(ah.v, b, acc[nt], 0, 0, 0);
            acc[nt] = __builtin_amdgcn_mfma_f32_16x16x32_bf16(al.v, b, acc[nt], 0, 0, 0);
        }
    }

    #pragma unroll
    for (int nt = 0; nt < 8; nt++) {
        const int col = nt * 16 + m16;
        const float bc = bias[col];
        #pragma unroll
        for (int r = 0; r < 4; r++) {
            int row = row0 + wv * 16 + quad * 4 + r;
            if (row < nrows) Ybf[(long)row * 128 + col] = f2bf(acc[nt][r] + bc);
        }
    }
}

// ---------------- MFMA GEMM (bf16 in): Y = Xbf @ W + bias (1 MFMA per tile) -----------
__global__ __launch_bounds__(256) void mfma_gemm_bf16_kernel(
    const unsigned short* __restrict__ Xbf, const unsigned short* __restrict__ Wt,
    const float* __restrict__ bias, float* __restrict__ Y, int nrows)
{
    __shared__ unsigned short Wl[128 * 128];
    const int t = threadIdx.x;
    const int lane = t & 63;
    const int wv = t >> 6;
    const int row0 = blockIdx.x * 64;
    const int m16 = lane & 15;
    const int quad = lane >> 4;

    {
        const uint4* Wg = (const uint4*)Wt;
        #pragma unroll
        for (int i = 0; i < 8; i++) {
            int gi = t + i * 256;
            int n = gi >> 4, g = gi & 15;
            uint4 v = Wg[gi];
            *(uint4*)&Wl[n * 128 + (((g ^ (n & 15)) << 3))] = v;
        }
    }

    const int arow = row0 + wv * 16 + m16;
    const bool valid = (arow < nrows);
    const uint4* X16 = (const uint4*)Xbf;
    union { uint4 u; bf16x8 v; } xr[4];
    #pragma unroll
    for (int kc = 0; kc < 4; kc++) {
        if (valid) xr[kc].u = X16[arow * 16 + kc * 4 + quad];
        else       xr[kc].u = make_uint4(0, 0, 0, 0);
    }
    __syncthreads();

    f32x4 acc[8];
    #pragma unroll
    for (int nt = 0; nt < 8; nt++) acc[nt] = (f32x4){0.f, 0.f, 0.f, 0.f};

    #pragma unroll
    for (int kc = 0; kc < 4; kc++) {
        const int sgbase = (kc * 4 + quad);
        #pragma unroll
        for (int nt = 0; nt < 8; nt++) {
            const int n = nt * 16 + m16;
            bf16x8 b = *(const bf16x8*)&Wl[n * 128 + ((sgbase ^ m16) << 3)];
            acc[nt] = __builtin_amdgcn_mfma_f32_16x16x32_bf16(xr[kc].v, b, acc[nt], 0, 0, 0);
        }
    }

    #pragma unroll
    for (int nt = 0; nt < 8; nt++) {
        const int col = nt * 16 + m16;
        const float bc = bias[col];
        #pragma unroll
        for (int r = 0; r < 4; r++) {
            int row = row0 + wv * 16 + quad * 4 + r;
            if (row < nrows) Y[(long)row * 128 + col] = acc[nt][r] + bc;
        }
    }
}

// ---------------- fused gather + attention: one wave per node, ONE latency exposure ----
// Round-15: identical dataflow to round-14 (dwordx4 = 4 edge-rows per instruction;
// both graphs' 8-instr groups issued before any consume) but ALL payload lives in
// individually NAMED scalars (a0..a7, b0..b7, na*, nb*, c1*, c2*) -- no per-thread
// arrays anywhere, so SROA cannot demote the pipeline to scratch (round-14's failure:
// VGPR=64 + 100 MB scratch WRITE_SIZE). Expect VGPR ~112, localMem 0.
#define GA_LOAD(dst, ndst, myc, nv, E, NB_) {                              \
    int e_ = (E); int ec_ = (e_ < (NB_)) ? e_ : 0;                         \
    int sx_ = __shfl((myc), ec_);                                          \
    float nq_ = __shfl((nv), ec_);                                         \
    ndst = (e_ < (NB_)) ? nq_ : 0.f;                                       \
    dst = *(const uint4*)(tblb + (((long)sx_) << 8) + sub16); }

#define GA_ISSUE8(p, myc, nv, J0, NB_)                                     \
    GA_LOAD(p##0, n##p##0, myc, nv, (J0) + 0  + qtr, NB_)                  \
    GA_LOAD(p##1, n##p##1, myc, nv, (J0) + 4  + qtr, NB_)                  \
    GA_LOAD(p##2, n##p##2, myc, nv, (J0) + 8  + qtr, NB_)                  \
    GA_LOAD(p##3, n##p##3, myc, nv, (J0) + 12 + qtr, NB_)                  \
    GA_LOAD(p##4, n##p##4, myc, nv, (J0) + 16 + qtr, NB_)                  \
    GA_LOAD(p##5, n##p##5, myc, nv, (J0) + 20 + qtr, NB_)                  \
    GA_LOAD(p##6, n##p##6, myc, nv, (J0) + 24 + qtr, NB_)                  \
    GA_LOAD(p##7, n##p##7, myc, nv, (J0) + 28 + qtr, NB_)

#define GA_CONS1(v, n, c)                                                  \
    c##0 = fmaf(bflo(v.x), n, c##0); c##1 = fmaf(bfhi(v.x), n, c##1);      \
    c##2 = fmaf(bflo(v.y), n, c##2); c##3 = fmaf(bfhi(v.y), n, c##3);      \
    c##4 = fmaf(bflo(v.z), n, c##4); c##5 = fmaf(bfhi(v.z), n, c##5);      \
    c##6 = fmaf(bflo(v.w), n, c##6); c##7 = fmaf(bfhi(v.w), n, c##7);

#define GA_CONS8(p, c)                                                     \
    GA_CONS1(p##0, n##p##0, c) GA_CONS1(p##1, n##p##1, c)                  \
    GA_CONS1(p##2, n##p##2, c) GA_CONS1(p##3, n##p##3, c)                  \
    GA_CONS1(p##4, n##p##4, c) GA_CONS1(p##5, n##p##5, c)                  \
    GA_CONS1(p##6, n##p##6, c) GA_CONS1(p##7, n##p##7, c)

__global__ __launch_bounds__(256, 4) void gather_attn_kernel(
    const unsigned short* __restrict__ hfb,
    const unsigned short* __restrict__ csr1, const int* __restrict__ start1,
    const int* __restrict__ deg1, const float* __restrict__ norm1,
    const unsigned short* __restrict__ csr2, const int* __restrict__ start2,
    const int* __restrict__ deg2, const float* __restrict__ norm2,
    const float* __restrict__ al, const float* __restrict__ ar,
    unsigned short* __restrict__ outb)
{
    const int lane = threadIdx.x & 63;
    const int wv = threadIdx.x >> 6;
    int node = blockIdx.x * 4 + wv;                // 12500*4 = 50000 exactly
    node = __builtin_amdgcn_readfirstlane(node);   // wave-uniform -> SGPR
    const char* tblb = (const char*)hfb;
    const int qtr = lane >> 4;                     // quarter handles edges == qtr mod 4
    const int sub16 = (lane & 15) * 16;            // byte offset within 256B row

    // own-feature row (attention self term): lane holds cols [8m, 8m+8), m = lane&15
    const uint4 ufv = *(const uint4*)(tblb + ((long)node << 8) + sub16);

    const int st1 = start1[node], dg1 = deg1[node];
    const int st2 = start2[node], dg2 = deg2[node];
    const int dgc1 = (dg1 < 64) ? dg1 : 64;
    const int dgc2 = (dg2 < 64) ? dg2 : 64;

    // coalesced edge-id loads + lane-parallel src-norm loads (1 VMEM each)
    int myc1 = (lane < dgc1) ? (int)csr1[st1 + lane] : 0;
    int myc2 = (lane < dgc2) ? (int)csr2[st2 + lane] : 0;
    const float nv1 = norm1[myc1];
    const float nv2 = norm2[myc2];

    float c10=0.f,c11=0.f,c12=0.f,c13=0.f,c14=0.f,c15=0.f,c16=0.f,c17=0.f;
    float c20=0.f,c21=0.f,c22=0.f,c23=0.f,c24=0.f,c25=0.f,c26=0.f,c27=0.f;

    uint4 a0,a1,a2,a3,a4,a5,a6,a7, b0,b1,b2,b3,b4,b5,b6,b7;
    float na0,na1,na2,na3,na4,na5,na6,na7, nb0,nb1,nb2,nb3,nb4,nb5,nb6,nb7;

    // ---- hot path: first <=32 edges of BOTH graphs in flight together ----
    GA_ISSUE8(a, myc1, nv1, 0, dgc1)
    GA_ISSUE8(b, myc2, nv2, 0, dgc2)
    __builtin_amdgcn_sched_barrier(0);
    GA_CONS8(a, c1)
    GA_CONS8(b, c2)

    // 32..64 edges (uniform branch; ~0.01% of nodes)
    if (dgc1 > 32) {
        GA_ISSUE8(a, myc1, nv1, 32, dgc1)
        __builtin_amdgcn_sched_barrier(0);
        GA_CONS8(a, c1)
    }
    if (dgc2 > 32) {
        GA_ISSUE8(b, myc2, nv2, 32, dgc2)
        __builtin_amdgcn_sched_barrier(0);
        GA_CONS8(b, c2)
    }

    // ---- cold remainder (deg > 64: essentially never; correctness only) ----
    for (int base = 64; base < dg1; base += 64) {
        const int nbv = ((dg1 - base) < 64) ? (dg1 - base) : 64;
        int myc = (lane < nbv) ? (int)csr1[st1 + base + lane] : 0;
        const float nv = norm1[myc];
        GA_ISSUE8(a, myc, nv, 0, nbv)
        __builtin_amdgcn_sched_barrier(0);
        GA_CONS8(a, c1)
        if (nbv > 32) {
            GA_ISSUE8(a, myc, nv, 32, nbv)
            __builtin_amdgcn_sched_barrier(0);
            GA_CONS8(a, c1)
        }
    }
    for (int base = 64; base < dg2; base += 64) {
        const int nbv = ((dg2 - base) < 64) ? (dg2 - base) : 64;
        int myc = (lane < nbv) ? (int)csr2[st2 + base + lane] : 0;
        const float nv = norm2[myc];
        GA_ISSUE8(b, myc, nv, 0, nbv)
        __builtin_amdgcn_sched_barrier(0);
        GA_CONS8(b, c2)
        if (nbv > 32) {
            GA_ISSUE8(b, myc, nv, 32, nbv)
            __builtin_amdgcn_sched_barrier(0);
            GA_CONS8(b, c2)
        }
    }

    float acc1[8] = {c10,c11,c12,c13,c14,c15,c16,c17};
    float acc2[8] = {c20,c21,c22,c23,c24,c25,c26,c27};

    // fold quarters: col c's total = sum over the 4 lanes {m, m+16, m+32, m+48}
    #pragma unroll
    for (int i = 0; i < 8; i++) {
        acc1[i] += __shfl_xor(acc1[i], 16);
        acc1[i] += __shfl_xor(acc1[i], 32);
        acc2[i] += __shfl_xor(acc2[i], 16);
        acc2[i] += __shfl_xor(acc2[i], 32);
    }

    // outer (dst) norm
    const float nn1 = norm1[node], nn2 = norm2[node];

    // attention combine in flat-reshape space: lane owns cols [8m, 8m+8), m = lane&15
    const int m = lane & 15;
    const int head = (node * 8 + (m >> 1)) / NN;
    const int hb = head * 16 + ((m & 1) << 3);     // hid base for this lane's 8 cols
    float uff[8] = { bflo(ufv.x), bfhi(ufv.x), bflo(ufv.y), bfhi(ufv.y),
                     bflo(ufv.z), bfhi(ufv.z), bflo(ufv.w), bfhi(ufv.w) };
    float s_ai = 0.f, s1 = 0.f, s2 = 0.f;
    #pragma unroll
    for (int i = 0; i < 8; i++) {
        acc1[i] *= nn1;
        acc2[i] *= nn2;
        const float avi = al[hb + i], rvi = ar[hb + i];
        s_ai = fmaf(uff[i], avi, s_ai);
        s1   = fmaf(acc1[i], rvi, s1);
        s2   = fmaf(acc2[i], rvi, s2);
    }
    // 16-col block = lanes {2t, 2t+1} within the 16-lane group
    s_ai += __shfl_xor(s_ai, 1);
    s1   += __shfl_xor(s1, 1);
    s2   += __shfl_xor(s2, 1);

    float x1 = s_ai + s1; x1 = x1 > 0.f ? x1 : 0.2f * x1;
    float x2 = s_ai + s2; x2 = x2 > 0.f ? x2 : 0.2f * x2;
    float e1 = fminf(expf(x1), 10.f);
    float e2 = fminf(expf(x2), 10.f);
    float inv = 1.f / (e1 + e2);
    float w1 = e1 * inv, w2 = e2 * inv;

    if (lane < 16) {   // quarters hold duplicates; quarter 0 writes 16x16B = 256B
        uint4 w;
        w.x = pack2(w1 * acc1[0] + w2 * acc2[0], w1 * acc1[1] + w2 * acc2[1]);
        w.y = pack2(w1 * acc1[2] + w2 * acc2[2], w1 * acc1[3] + w2 * acc2[3]);
        w.z = pack2(w1 * acc1[4] + w2 * acc2[4], w1 * acc1[5] + w2 * acc2[5]);
        w.w = pack2(w1 * acc1[6] + w2 * acc2[6], w1 * acc1[7] + w2 * acc2[7]);
        *(uint4*)((char*)outb + ((long)node << 8) + m * 16) = w;
    }
}

extern "C" void kernel_launch(void* const* d_in, const int* in_sizes, int n_in,
                              void* d_out, int out_size, void* d_ws, size_t ws_size,
                              hipStream_t stream)
{
    const float* h     = (const float*)d_in[0];
    const int*   src1  = (const int*)  d_in[1];
    const int*   dst1  = (const int*)  d_in[2];
    const int*   src2  = (const int*)  d_in[3];
    const int*   dst2  = (const int*)  d_in[4];
    const float* norm1 = (const float*)d_in[5];
    const float* norm2 = (const float*)d_in[6];
    const float* W_lin = (const float*)d_in[7];
    const float* b_lin = (const float*)d_in[8];
    const float* al    = (const float*)d_in[9];
    const float* ar    = (const float*)d_in[10];
    const float* W_fc  = (const float*)d_in[11];
    const float* b_fc  = (const float*)d_in[12];
    float* out = (float*)d_out;

    // workspace layout
    unsigned short* hfb  = (unsigned short*)d_ws;         // NN*128 bf16 = 12.8 MB
    unsigned short* outbf = hfb + (size_t)NN * 128;       // NN*128 bf16 = 12.8 MB
    unsigned int* bin1 = (unsigned int*)(outbf + (size_t)NN * 128);  // NE u32
    unsigned int* bin2 = bin1 + NE;                       // NE u32
    unsigned short* csr1 = (unsigned short*)(bin2 + NE);  // NE u16
    unsigned short* csr2 = csr1 + NE;                     // NE u16
    unsigned short* WtL  = csr2 + NE;                     // 16384 u16
    unsigned short* WtF  = WtL + 128 * 128;               // 16384 u16
    int* histG  = (int*)(WtF + 128 * 128);                // NBLK*NBG ints = 200 KB
    int* btot   = histG + NBLK * NBG;                     // 392
    int* bbase  = btot + NBG;                             // 392
    int* start1 = bbase + NBG;
    int* start2 = start1 + NN;
    int* deg1   = start2 + NN;
    int* deg2   = deg1 + NN;

    // 1) histogram (chunk-major) + one-time W bf16 conversion
    histA_kernel<<<NBLK + 2, 1024, 0, stream>>>(dst1, dst2, histG, W_lin, W_fc, WtL, WtF);

    // 2) hfb = bf16(h @ W_lin + b_lin)
    mfma_gemm_kernel<<<(NN + 63) / 64, 256, 0, stream>>>(h, WtL, b_lin, hfb, NN);

    // 3) deterministic scatter (computes its own prefix sums; publishes bbase/btot)
    scatterC_kernel<<<NBLK, 1024, 0, stream>>>(src1, dst1, src2, dst2, histG,
                                               bbase, btot, bin1, bin2);

    // 4) per-bucket LDS counting sort -> u16 CSR + start/deg
    bucket_sort_kernel<<<NBG, 256, 0, stream>>>(bin1, bin2, bbase, btot,
                                                csr1, start1, deg1,
                                                csr2, start2, deg2);

    // 5) fused gather (both graphs) + attention combine -> bf16
    gather_attn_kernel<<<12500, 256, 0, stream>>>(
        hfb,
        csr1, start1, deg1, norm1,
        csr2, start2, deg2, norm2,
        al, ar, outbf);

    // 6) out = outbf @ W_fc + b_fc
    mfma_gemm_bf16_kernel<<<(NN + 63) / 64, 256, 0, stream>>>(outbf, WtF, b_fc, out, NN);
}

// Round 8
// 249.796 us; speedup vs baseline: 1.0777x; 1.0777x over previous
//
#include <hip/hip_runtime.h>

#define NN 50000
#define NE 800000
#define NB 196          // ceil(NN/256) node buckets of 256 nodes
#define NBG 392         // 2*NB (both graphs)
#define NBLK 128        // edge chunks
#define CHUNK 6250      // NE / NBLK exactly
#define MAXB 6144       // max edges per bucket (mean 4081; +32 sigma)
// D = 128 features, HEADS=8, HID=16

typedef __bf16 bf16x8 __attribute__((ext_vector_type(8)));
typedef float  f32x4  __attribute__((ext_vector_type(4)));

__device__ __forceinline__ unsigned short f2bf(float x) {
    unsigned u = __float_as_uint(x);
    return (unsigned short)((u + 0x7FFFu + ((u >> 16) & 1u)) >> 16);   // RNE
}
__device__ __forceinline__ float bflo(unsigned u) { return __uint_as_float(u << 16); }
__device__ __forceinline__ float bfhi(unsigned u) { return __uint_as_float(u & 0xFFFF0000u); }
__device__ __forceinline__ unsigned pack2(float a, float b) {
    return (unsigned)f2bf(a) | ((unsigned)f2bf(b) << 16);
}

// ---------------- phase A: per-chunk LDS histogram (chunk-major histG) + W convert ----
__global__ __launch_bounds__(1024) void histA_kernel(
    const int* __restrict__ dst1, const int* __restrict__ dst2, int* __restrict__ histG,
    const float* __restrict__ Wa, const float* __restrict__ Wb,
    unsigned short* __restrict__ Wta, unsigned short* __restrict__ Wtb)
{
    const int t = threadIdx.x, blk = blockIdx.x;
    if (blk >= NBLK) {   // W convert
        const float* W = (blk - NBLK) ? Wb : Wa;
        unsigned short* Wt = (blk - NBLK) ? Wtb : Wta;
        for (int j = t; j < 128 * 128; j += 1024) {
            int n = j >> 7, k = j & 127;
            Wt[j] = f2bf(W[k * 128 + n]);
        }
        return;
    }
    __shared__ int h[NBG];
    for (int i = t; i < NBG; i += 1024) h[i] = 0;
    __syncthreads();
    const int base = blk * CHUNK;
    for (int i = t; i < CHUNK; i += 1024) {
        atomicAdd(&h[dst1[base + i] >> 8], 1);
        atomicAdd(&h[NB + (dst2[base + i] >> 8)], 1);
    }
    __syncthreads();
    for (int i = t; i < NBG; i += 1024)
        histG[blk * NBG + i] = h[i];
}

// ---------------- phase C: scatter with LOCAL prefix computation ---------------------
__global__ __launch_bounds__(1024) void scatterC_kernel(
    const int* __restrict__ src1, const int* __restrict__ dst1,
    const int* __restrict__ src2, const int* __restrict__ dst2,
    const int* __restrict__ histG,
    int* __restrict__ gbbase, int* __restrict__ gbtot,
    unsigned int* __restrict__ bin1, unsigned int* __restrict__ bin2)
{
    __shared__ int s[512];
    __shared__ int pos[NBG];
    const int t = threadIdx.x, blk = blockIdx.x;

    int total_i = 0, pref_i = 0;
    if (t < NBG) {
        for (int c = 0; c < NBLK; c++) {
            int v = histG[c * NBG + t];          // coalesced across t
            total_i += v;
            if (c < blk) pref_i += v;
        }
    }
    if (t < 512) s[t] = (t < NBG) ? total_i : 0;
    __syncthreads();
    for (int off = 1; off < 512; off <<= 1) {
        int x = 0;
        if (t < 512 && t >= off) x = s[t - off];
        __syncthreads();
        if (t < 512) s[t] += x;
        __syncthreads();
    }
    const int sumG1 = s[NB - 1];   // inclusive over graph-1 buckets
    if (t < NBG) {
        int excl = s[t] - total_i;
        int bb = excl - ((t >= NB) ? sumG1 : 0);   // per-graph exclusive base
        pos[t] = bb + pref_i;
        if (blk == 0) { gbbase[t] = bb; gbtot[t] = total_i; }
    }
    __syncthreads();

    const int base = blk * CHUNK;
    for (int i = t; i < CHUNK; i += 1024) {
        int d = dst1[base + i], sv = src1[base + i];
        int slot = atomicAdd(&pos[d >> 8], 1);
        bin1[slot] = ((unsigned)(d & 255) << 16) | (unsigned)sv;
        d = dst2[base + i]; sv = src2[base + i];
        slot = atomicAdd(&pos[NB + (d >> 8)], 1);
        bin2[slot] = ((unsigned)(d & 255) << 16) | (unsigned)sv;
    }
}

// ---------------- bucket sort: LDS counting sort per bucket, coalesced csr flush ------
__global__ __launch_bounds__(256) void bucket_sort_kernel(
    const unsigned int* __restrict__ bin1, const unsigned int* __restrict__ bin2,
    const int* __restrict__ bbase, const int* __restrict__ btot,
    unsigned short* __restrict__ csr1, int* __restrict__ start1, int* __restrict__ deg1,
    unsigned short* __restrict__ csr2, int* __restrict__ start2, int* __restrict__ deg2)
{
    __shared__ int lcnt[256];
    __shared__ int sc[256];
    __shared__ int oat[256];
    __shared__ unsigned short outb[MAXB];
    const int t = threadIdx.x;
    const int g = (blockIdx.x >= NB) ? 1 : 0;
    const int b = blockIdx.x - g * NB;
    const unsigned int* bin = g ? bin2 : bin1;
    unsigned short* csr = g ? csr2 : csr1;
    int* start = g ? start2 : start1;
    int* deg   = g ? deg2 : deg1;

    const int base = bbase[g * NB + b];
    const int tot = min(btot[g * NB + b], MAXB);

    lcnt[t] = 0;
    __syncthreads();
    for (int i = t; i < tot; i += 256) atomicAdd(&lcnt[bin[base + i] >> 16], 1);
    __syncthreads();
    sc[t] = lcnt[t];
    __syncthreads();
    for (int off = 1; off < 256; off <<= 1) {
        int x = (t >= off) ? sc[t - off] : 0;
        __syncthreads();
        sc[t] += x;
        __syncthreads();
    }
    const int ex = sc[t] - lcnt[t];
    oat[t] = ex;
    __syncthreads();
    for (int i = t; i < tot; i += 256) {
        unsigned v = bin[base + i];
        int slot = atomicAdd(&oat[v >> 16], 1);
        outb[slot] = (unsigned short)(v & 0xFFFFu);
    }
    __syncthreads();
    for (int i = t; i < tot; i += 256) csr[base + i] = outb[i];
    int nd = b * 256 + t;
    if (nd < NN) { start[nd] = base + ex; deg[nd] = lcnt[t]; }
}

// ---------------- MFMA GEMM (fp32 in): halves -> YA (cols 0-63), YB (cols 64-127) -----
__global__ __launch_bounds__(256) void mfma_gemm_kernel(
    const float* __restrict__ X, const unsigned short* __restrict__ Wt,
    const float* __restrict__ bias,
    unsigned short* __restrict__ YA, unsigned short* __restrict__ YB, int nrows)
{
    __shared__ unsigned short Wl[128 * 128];   // 32 KB, granule-swizzled
    const int t = threadIdx.x;
    const int lane = t & 63;
    const int wv = t >> 6;
    const int row0 = blockIdx.x * 64;
    const int m16 = lane & 15;
    const int quad = lane >> 4;

    {
        const uint4* Wg = (const uint4*)Wt;
        #pragma unroll
        for (int i = 0; i < 8; i++) {
            int gi = t + i * 256;
            int n = gi >> 4, g = gi & 15;
            uint4 v = Wg[gi];
            *(uint4*)&Wl[n * 128 + (((g ^ (n & 15)) << 3))] = v;
        }
    }

    const int arow = row0 + wv * 16 + m16;
    const bool valid = (arow < nrows);
    const float4* X4 = (const float4*)X;
    float4 xr[8];
    #pragma unroll
    for (int kc = 0; kc < 4; kc++) {
        if (valid) {
            int gidx = arow * 32 + kc * 8 + quad * 2;
            xr[kc * 2]     = X4[gidx];
            xr[kc * 2 + 1] = X4[gidx + 1];
        } else {
            xr[kc * 2] = xr[kc * 2 + 1] = make_float4(0.f, 0.f, 0.f, 0.f);
        }
    }
    __syncthreads();

    f32x4 acc[8];
    #pragma unroll
    for (int nt = 0; nt < 8; nt++) acc[nt] = (f32x4){0.f, 0.f, 0.f, 0.f};

    #pragma unroll
    for (int kc = 0; kc < 4; kc++) {
        union { unsigned short u[8]; bf16x8 v; } ah, al;
        float f[8] = { xr[kc*2].x, xr[kc*2].y, xr[kc*2].z, xr[kc*2].w,
                       xr[kc*2+1].x, xr[kc*2+1].y, xr[kc*2+1].z, xr[kc*2+1].w };
        #pragma unroll
        for (int j = 0; j < 8; j++) {
            unsigned u = __float_as_uint(f[j]);
            ah.u[j] = (unsigned short)(u >> 16);
            al.u[j] = f2bf(f[j] - __uint_as_float(u & 0xFFFF0000u));
        }
        const int sgbase = (kc * 4 + quad);
        #pragma unroll
        for (int nt = 0; nt < 8; nt++) {
            const int n = nt * 16 + m16;
            bf16x8 b = *(const bf16x8*)&Wl[n * 128 + ((sgbase ^ m16) << 3)];
            acc[nt] = __builtin_amdgcn_mfma_f32_16x16x32_bf16(ah.v, b, acc[nt], 0, 0, 0);
            acc[nt] = __builtin_amdgcn_mfma_f32_16x16x32_bf16(al.v, b, acc[nt], 0, 0, 0);
        }
    }

    #pragma unroll
    for (int nt = 0; nt < 8; nt++) {
        const int col = nt * 16 + m16;
        const float bc = bias[col];
        #pragma unroll
        for (int r = 0; r < 4; r++) {
            int row = row0 + wv * 16 + quad * 4 + r;
            if (row < nrows) {
                float val = acc[nt][r] + bc;
                if (col < 64) YA[(long)row * 64 + col]        = f2bf(val);
                else          YB[(long)row * 64 + (col - 64)] = f2bf(val);
            }
        }
    }
}

// ---------------- MFMA GEMM (bf16 in): Y = Xbf @ W + bias (1 MFMA per tile) -----------
__global__ __launch_bounds__(256) void mfma_gemm_bf16_kernel(
    const unsigned short* __restrict__ Xbf, const unsigned short* __restrict__ Wt,
    const float* __restrict__ bias, float* __restrict__ Y, int nrows)
{
    __shared__ unsigned short Wl[128 * 128];
    const int t = threadIdx.x;
    const int lane = t & 63;
    const int wv = t >> 6;
    const int row0 = blockIdx.x * 64;
    const int m16 = lane & 15;
    const int quad = lane >> 4;

    {
        const uint4* Wg = (const uint4*)Wt;
        #pragma unroll
        for (int i = 0; i < 8; i++) {
            int gi = t + i * 256;
            int n = gi >> 4, g = gi & 15;
            uint4 v = Wg[gi];
            *(uint4*)&Wl[n * 128 + (((g ^ (n & 15)) << 3))] = v;
        }
    }

    const int arow = row0 + wv * 16 + m16;
    const bool valid = (arow < nrows);
    const uint4* X16 = (const uint4*)Xbf;
    union { uint4 u; bf16x8 v; } xr[4];
    #pragma unroll
    for (int kc = 0; kc < 4; kc++) {
        if (valid) xr[kc].u = X16[arow * 16 + kc * 4 + quad];
        else       xr[kc].u = make_uint4(0, 0, 0, 0);
    }
    __syncthreads();

    f32x4 acc[8];
    #pragma unroll
    for (int nt = 0; nt < 8; nt++) acc[nt] = (f32x4){0.f, 0.f, 0.f, 0.f};

    #pragma unroll
    for (int kc = 0; kc < 4; kc++) {
        const int sgbase = (kc * 4 + quad);
        #pragma unroll
        for (int nt = 0; nt < 8; nt++) {
            const int n = nt * 16 + m16;
            bf16x8 b = *(const bf16x8*)&Wl[n * 128 + ((sgbase ^ m16) << 3)];
            acc[nt] = __builtin_amdgcn_mfma_f32_16x16x32_bf16(xr[kc].v, b, acc[nt], 0, 0, 0);
        }
    }

    #pragma unroll
    for (int nt = 0; nt < 8; nt++) {
        const int col = nt * 16 + m16;
        const float bc = bias[col];
        #pragma unroll
        for (int r = 0; r < 4; r++) {
            int row = row0 + wv * 16 + quad * 4 + r;
            if (row < nrows) Y[(long)row * 128 + col] = acc[nt][r] + bc;
        }
    }
}

// ---------------- fused gather + attention: wave per (node, half), hardened ------------
// Round-17 (hardened r7): half tables + XCD steer (r4-proven); grp-of-8 dwordx4 gather
// covering only e < min(deg,32) in ONE issue->consume exposure (fits the 64-VGPR cap);
// norms captured at ISSUE into named floats (r6-proven pattern, no consume shuffles);
// ALL edges >= 32 go through a serial scalar tail placed AFTER the grp-fold, so every
// lane adds the tail exactly once to its complete per-col copy (no fold-multiplicity
// hazard; replaces r7's suspect vectorized >32 branch).
#define GA_LOAD(dst, ndst, myc, nv, E, NB_) {                              \
    int e_ = (E); int ec_ = (e_ < (NB_)) ? e_ : 0;                         \
    int sx_ = __shfl((myc), ec_);                                          \
    float nq_ = __shfl((nv), ec_);                                         \
    ndst = (e_ < (NB_)) ? nq_ : 0.f;                                       \
    dst = *(const uint4*)(tblb + (((long)sx_) << 7) + sub16); }

#define GA_ISSUE4(p, myc, nv, NB_)                                         \
    GA_LOAD(p##0, n##p##0, myc, nv, 0  + grp, NB_)                         \
    GA_LOAD(p##1, n##p##1, myc, nv, 8  + grp, NB_)                         \
    GA_LOAD(p##2, n##p##2, myc, nv, 16 + grp, NB_)                         \
    GA_LOAD(p##3, n##p##3, myc, nv, 24 + grp, NB_)

#define GA_CONS1(v, n, c)                                                  \
    c##0 = fmaf(bflo(v.x), n, c##0); c##1 = fmaf(bfhi(v.x), n, c##1);      \
    c##2 = fmaf(bflo(v.y), n, c##2); c##3 = fmaf(bfhi(v.y), n, c##3);      \
    c##4 = fmaf(bflo(v.z), n, c##4); c##5 = fmaf(bfhi(v.z), n, c##5);      \
    c##6 = fmaf(bflo(v.w), n, c##6); c##7 = fmaf(bfhi(v.w), n, c##7);

#define GA_CONS4(p, c)                                                     \
    GA_CONS1(p##0, n##p##0, c) GA_CONS1(p##1, n##p##1, c)                  \
    GA_CONS1(p##2, n##p##2, c) GA_CONS1(p##3, n##p##3, c)

__global__ __launch_bounds__(256) void gather_attn_kernel(
    const unsigned short* __restrict__ hfA, const unsigned short* __restrict__ hfB,
    const unsigned short* __restrict__ csr1, const int* __restrict__ start1,
    const int* __restrict__ deg1, const float* __restrict__ norm1,
    const unsigned short* __restrict__ csr2, const int* __restrict__ start2,
    const int* __restrict__ deg2, const float* __restrict__ norm2,
    const float* __restrict__ al, const float* __restrict__ ar,
    unsigned short* __restrict__ outb)
{
    const int lane = threadIdx.x & 63;
    const int wv = threadIdx.x >> 6;
    const int b = blockIdx.x;
    const int half = (b >> 2) & 1;                 // XCD steer: b%8<4 -> half0
    const int lb = (b >> 3) * 4 + (b & 3);         // local block within half [0,12500)
    int node = lb * 4 + wv;                        // 12500*4 = 50000 exactly
    node = __builtin_amdgcn_readfirstlane(node);   // wave-uniform -> SGPR
    const char* tblb = (const char*)(half ? hfB : hfA);
    const int grp = lane >> 3;                     // 8-lane group = one 128B row
    const int sub16 = (lane & 7) * 16;             // byte offset within row

    const int st1 = start1[node], dg1 = deg1[node];
    const int st2 = start2[node], dg2 = deg2[node];
    const int dgc1 = (dg1 < 32) ? dg1 : 32;
    const int dgc2 = (dg2 < 32) ? dg2 : 32;

    // coalesced edge-id loads + lane-parallel src-norm loads (1 VMEM each)
    int myc1 = (lane < dgc1) ? (int)csr1[st1 + lane] : 0;
    int myc2 = (lane < dgc2) ? (int)csr2[st2 + lane] : 0;
    const float nv1 = norm1[myc1];
    const float nv2 = norm2[myc2];

    float c10=0.f,c11=0.f,c12=0.f,c13=0.f,c14=0.f,c15=0.f,c16=0.f,c17=0.f;
    float c20=0.f,c21=0.f,c22=0.f,c23=0.f,c24=0.f,c25=0.f,c26=0.f,c27=0.f;
    uint4 a0, a1, a2, a3, b0, b1, b2, b3;
    float na0, na1, na2, na3, nb0, nb1, nb2, nb3;

    // ---- hot path: first <=32 edges of BOTH graphs + self row in ONE exposure ----
    GA_ISSUE4(a, myc1, nv1, dgc1)
    GA_ISSUE4(b, myc2, nv2, dgc2)
    const uint4 ufv = *(const uint4*)(tblb + ((long)node << 7) + sub16);
    __builtin_amdgcn_sched_barrier(0);
    GA_CONS4(a, c1)
    GA_CONS4(b, c2)

    // ---- fold the 8 row-groups: sum lanes {mm, mm+8, ..., mm+56} ----
    float acc1[8] = {c10,c11,c12,c13,c14,c15,c16,c17};
    float acc2[8] = {c20,c21,c22,c23,c24,c25,c26,c27};
    #pragma unroll
    for (int i = 0; i < 8; i++) {
        acc1[i] += __shfl_xor(acc1[i], 8);
        acc1[i] += __shfl_xor(acc1[i], 16);
        acc1[i] += __shfl_xor(acc1[i], 32);
        acc2[i] += __shfl_xor(acc2[i], 8);
        acc2[i] += __shfl_xor(acc2[i], 16);
        acc2[i] += __shfl_xor(acc2[i], 32);
    }

    // ---- serial tail for e >= 32 (P(deg>32) ~ 1e-4): AFTER the fold, so each lane
    // adds the contribution exactly once to its complete copy ----
    for (int e = 32; e < dg1; e++) {
        int s = (int)csr1[st1 + e];                 // uniform broadcast load
        float n = norm1[s];
        uint4 v = *(const uint4*)(tblb + ((long)s << 7) + sub16);
        acc1[0] = fmaf(bflo(v.x), n, acc1[0]); acc1[1] = fmaf(bfhi(v.x), n, acc1[1]);
        acc1[2] = fmaf(bflo(v.y), n, acc1[2]); acc1[3] = fmaf(bfhi(v.y), n, acc1[3]);
        acc1[4] = fmaf(bflo(v.z), n, acc1[4]); acc1[5] = fmaf(bfhi(v.z), n, acc1[5]);
        acc1[6] = fmaf(bflo(v.w), n, acc1[6]); acc1[7] = fmaf(bfhi(v.w), n, acc1[7]);
    }
    for (int e = 32; e < dg2; e++) {
        int s = (int)csr2[st2 + e];
        float n = norm2[s];
        uint4 v = *(const uint4*)(tblb + ((long)s << 7) + sub16);
        acc2[0] = fmaf(bflo(v.x), n, acc2[0]); acc2[1] = fmaf(bfhi(v.x), n, acc2[1]);
        acc2[2] = fmaf(bflo(v.y), n, acc2[2]); acc2[3] = fmaf(bfhi(v.y), n, acc2[3]);
        acc2[4] = fmaf(bflo(v.z), n, acc2[4]); acc2[5] = fmaf(bfhi(v.z), n, acc2[5]);
        acc2[6] = fmaf(bflo(v.w), n, acc2[6]); acc2[7] = fmaf(bfhi(v.w), n, acc2[7]);
    }

    // outer (dst) norm
    const float nn1 = norm1[node], nn2 = norm2[node];

    // attention combine: lane owns cols c = 64*half + 8*mm + i, i=0..7 (mm = lane&7)
    const int mm = lane & 7;
    const int cc = half * 4 + (mm >> 1);           // c>>4, same for all 8 cols
    const int head = (node * 8 + cc) / NN;
    const int hb = head * 16 + ((mm & 1) << 3);    // hid base for this lane's 8 cols
    float uff[8] = { bflo(ufv.x), bfhi(ufv.x), bflo(ufv.y), bfhi(ufv.y),
                     bflo(ufv.z), bfhi(ufv.z), bflo(ufv.w), bfhi(ufv.w) };
    float s_ai = 0.f, s1 = 0.f, s2 = 0.f;
    #pragma unroll
    for (int i = 0; i < 8; i++) {
        acc1[i] *= nn1;
        acc2[i] *= nn2;
        const float avi = al[hb + i], rvi = ar[hb + i];
        s_ai = fmaf(uff[i], avi, s_ai);
        s1   = fmaf(acc1[i], rvi, s1);
        s2   = fmaf(acc2[i], rvi, s2);
    }
    // 16-col chunk = lane pair (mm = 2t, 2t+1)
    s_ai += __shfl_xor(s_ai, 1);
    s1   += __shfl_xor(s1, 1);
    s2   += __shfl_xor(s2, 1);

    float x1 = s_ai + s1; x1 = x1 > 0.f ? x1 : 0.2f * x1;
    float x2 = s_ai + s2; x2 = x2 > 0.f ? x2 : 0.2f * x2;
    float e1 = fminf(expf(x1), 10.f);
    float e2 = fminf(expf(x2), 10.f);
    float inv = 1.f / (e1 + e2);
    float w1 = e1 * inv, w2 = e2 * inv;

    if (lane < 8) {    // groups hold duplicates; group 0 writes 8 x 16B = 128B
        uint4 w;
        w.x = pack2(w1 * acc1[0] + w2 * acc2[0], w1 * acc1[1] + w2 * acc2[1]);
        w.y = pack2(w1 * acc1[2] + w2 * acc2[2], w1 * acc1[3] + w2 * acc2[3]);
        w.z = pack2(w1 * acc1[4] + w2 * acc2[4], w1 * acc1[5] + w2 * acc2[5]);
        w.w = pack2(w1 * acc1[6] + w2 * acc2[6], w1 * acc1[7] + w2 * acc2[7]);
        *(uint4*)((char*)outb + ((long)node << 8) + half * 128 + mm * 16) = w;
    }
}

extern "C" void kernel_launch(void* const* d_in, const int* in_sizes, int n_in,
                              void* d_out, int out_size, void* d_ws, size_t ws_size,
                              hipStream_t stream)
{
    const float* h     = (const float*)d_in[0];
    const int*   src1  = (const int*)  d_in[1];
    const int*   dst1  = (const int*)  d_in[2];
    const int*   src2  = (const int*)  d_in[3];
    const int*   dst2  = (const int*)  d_in[4];
    const float* norm1 = (const float*)d_in[5];
    const float* norm2 = (const float*)d_in[6];
    const float* W_lin = (const float*)d_in[7];
    const float* b_lin = (const float*)d_in[8];
    const float* al    = (const float*)d_in[9];
    const float* ar    = (const float*)d_in[10];
    const float* W_fc  = (const float*)d_in[11];
    const float* b_fc  = (const float*)d_in[12];
    float* out = (float*)d_out;

    // workspace layout
    unsigned short* hfA  = (unsigned short*)d_ws;         // NN*64 bf16 = 6.4 MB (cols 0-63)
    unsigned short* hfB  = hfA + (size_t)NN * 64;         // NN*64 bf16 = 6.4 MB (cols 64-127)
    unsigned short* outbf = hfB + (size_t)NN * 64;        // NN*128 bf16 = 12.8 MB
    unsigned int* bin1 = (unsigned int*)(outbf + (size_t)NN * 128);  // NE u32
    unsigned int* bin2 = bin1 + NE;                       // NE u32
    unsigned short* csr1 = (unsigned short*)(bin2 + NE);  // NE u16
    unsigned short* csr2 = csr1 + NE;                     // NE u16
    unsigned short* WtL  = csr2 + NE;                     // 16384 u16
    unsigned short* WtF  = WtL + 128 * 128;               // 16384 u16
    int* histG  = (int*)(WtF + 128 * 128);                // NBLK*NBG ints = 200 KB
    int* btot   = histG + NBLK * NBG;                     // 392
    int* bbase  = btot + NBG;                             // 392
    int* start1 = bbase + NBG;
    int* start2 = start1 + NN;
    int* deg1   = start2 + NN;
    int* deg2   = deg1 + NN;

    // 1) histogram (chunk-major) + one-time W bf16 conversion
    histA_kernel<<<NBLK + 2, 1024, 0, stream>>>(dst1, dst2, histG, W_lin, W_fc, WtL, WtF);

    // 2) hfA/hfB = bf16(h @ W_lin + b_lin), split by column half
    mfma_gemm_kernel<<<(NN + 63) / 64, 256, 0, stream>>>(h, WtL, b_lin, hfA, hfB, NN);

    // 3) deterministic scatter (computes its own prefix sums; publishes bbase/btot)
    scatterC_kernel<<<NBLK, 1024, 0, stream>>>(src1, dst1, src2, dst2, histG,
                                               bbase, btot, bin1, bin2);

    // 4) per-bucket LDS counting sort -> u16 CSR + start/deg
    bucket_sort_kernel<<<NBG, 256, 0, stream>>>(bin1, bin2, bbase, btot,
                                                csr1, start1, deg1,
                                                csr2, start2, deg2);

    // 5) fused gather (both graphs, split halves, XCD-steered) + attention -> bf16
    gather_attn_kernel<<<25000, 256, 0, stream>>>(
        hfA, hfB,
        csr1, start1, deg1, norm1,
        csr2, start2, deg2, norm2,
        al, ar, outbf);

    // 6) out = outbf @ W_fc + b_fc
    mfma_gemm_bf16_kernel<<<(NN + 63) / 64, 256, 0, stream>>>(outbf, WtF, b_fc, out, NN);
}